// Round 4
// baseline (232.256 us; speedup 1.0000x reference)
//
#include <hip/hip_runtime.h>
#include <hip/hip_bf16.h>

// GCNConv forward: out = D^-1/2 (A+I) D^-1/2 (x W^T) + b
// N=100000, E=1600000, DIM=128. fp32 in/out, edge_index as int32.
//
// R9 (resubmit; prior round hit GPUAcquisitionTimeout, never ran):
// scatter rebuilt as packed-uint32 LDS multisplit (line-dense 64B flushes,
// one pass, 4B/edge instead of 8B + amplification). Bins refined 512->256
// nodes (NB=391): halves csr serial sort path, doubles its parallelism; sort
// hidden under 8-wave GEMM role in the same dispatch.
//   memset(cursors) -> [scatter_ms || wconv] -> [csr || gemm] -> aggregate

#define DIM 128
#define BINSHIFT 8
#define BINSZ 256            // nodes per bin
#define NB 391               // ceil(100000/256)
#define CAPB 8192            // edges per bin capacity (mean 4096, sd ~64)
#define BUFCAP 40            // LDS staging slots per bin (carry<=15 + round max)
#define SBLK 128             // scatter blocks
#define ROUND 2048           // edges per multisplit round per block
#define WSTRIDE 136          // shorts per LDS row in gemm epilogue buffer

typedef __attribute__((ext_vector_type(8))) short short8;
typedef __attribute__((ext_vector_type(4))) float f32x4;
typedef __attribute__((ext_vector_type(4))) unsigned short ushort4v;

__device__ inline unsigned short f2bf(float f) {
    unsigned u = __builtin_bit_cast(unsigned, f);
    return (unsigned short)((u + 0x7FFFu + ((u >> 16) & 1u)) >> 16);
}

// acc[j] += s * bf16_to_f32(v[j]) for 8 bf16 packed in a uint4
__device__ inline void bf8_axpy(uint4 v, float s, float* acc) {
    acc[0] = fmaf(s, __builtin_bit_cast(float, v.x << 16), acc[0]);
    acc[1] = fmaf(s, __builtin_bit_cast(float, v.x & 0xFFFF0000u), acc[1]);
    acc[2] = fmaf(s, __builtin_bit_cast(float, v.y << 16), acc[2]);
    acc[3] = fmaf(s, __builtin_bit_cast(float, v.y & 0xFFFF0000u), acc[3]);
    acc[4] = fmaf(s, __builtin_bit_cast(float, v.z << 16), acc[4]);
    acc[5] = fmaf(s, __builtin_bit_cast(float, v.z & 0xFFFF0000u), acc[5]);
    acc[6] = fmaf(s, __builtin_bit_cast(float, v.w << 16), acc[6]);
    acc[7] = fmaf(s, __builtin_bit_cast(float, v.w & 0xFFFF0000u), acc[7]);
}

// ---- K1: multisplit scatter (blocks 0..SBLK-1) || W->bf16 (last 2 blocks) --
// Deposit packed (ldst<<17|src) into per-bin LDS buffers; flush 16-entry (64B)
// groups to gapped bin regions via per-bin global cursors. Overflow -> direct
// single write (rare; correctness preserved, order within bin irrelevant).
__global__ __launch_bounds__(512) void scatter_ms(const int* __restrict__ ei, int E,
                                                  int* __restrict__ binCursor,
                                                  unsigned* __restrict__ binned,
                                                  const float* __restrict__ W,
                                                  unsigned short* __restrict__ wbf) {
    int t = threadIdx.x;
    if ((int)blockIdx.x >= SBLK) {
        // ---- wconv role: 2 blocks x 512 thr x 4 float4 = 4096 float4 = 16K w
        int base = ((int)blockIdx.x - SBLK) * 2048 + t * 4;
#pragma unroll
        for (int i = 0; i < 4; ++i) {
            float4 w4 = ((const float4*)W)[base + i];
            ushort4v o; o.x = f2bf(w4.x); o.y = f2bf(w4.y); o.z = f2bf(w4.z); o.w = f2bf(w4.w);
            ((ushort4v*)wbf)[base + i] = o;
        }
        return;
    }

    __shared__ int cnt[NB];
    __shared__ unsigned buf[NB * BUFCAP];   // 62.6 KB
    for (int i = t; i < NB; i += 512) cnt[i] = 0;
    __syncthreads();

    int chunk = (E + SBLK - 1) / SBLK;      // 12500
    int base = blockIdx.x * chunk;
    int end = min(E, base + chunk);

    for (int rb = base; rb < end; rb += ROUND) {
        int re = min(end, rb + ROUND);
        // deposit
        for (int i = rb + t; i < re; i += 512) {
            int s = ei[i];
            int d = ei[E + i];
            int b = d >> BINSHIFT;
            unsigned p = ((unsigned)(d & (BINSZ - 1)) << 17) | (unsigned)s;
            int pos = atomicAdd(&cnt[b], 1);
            if (pos < BUFCAP) buf[b * BUFCAP + pos] = p;
            else binned[(size_t)b * CAPB + atomicAdd(&binCursor[b], 1)] = p;
        }
        __syncthreads();
        // flush full 16-entry groups (64B lines)
        for (int b = t; b < NB; b += 512) {
            int c = min(cnt[b], BUFCAP);
            int full = c & ~15;
            if (full > 0) {
                int gbase = atomicAdd(&binCursor[b], full);
                unsigned* gp = binned + (size_t)b * CAPB + gbase;
                const unsigned* lp = &buf[b * BUFCAP];
                if ((gbase & 3) == 0) {
                    for (int g = 0; g < full; g += 4)
                        *(uint4*)(gp + g) = *(const uint4*)(lp + g);
                } else {
                    for (int g = 0; g < full; ++g) gp[g] = lp[g];
                }
                int rem = c - full;
                for (int j = 0; j < rem; ++j)
                    buf[b * BUFCAP + j] = buf[b * BUFCAP + full + j];
                cnt[b] = rem;
            } else {
                cnt[b] = c;
            }
        }
        __syncthreads();
    }
    // final remainder flush (singles; bin regions L2-hot)
    for (int b = t; b < NB; b += 512) {
        int c = min(cnt[b], BUFCAP);
        if (c > 0) {
            int gbase = atomicAdd(&binCursor[b], c);
            unsigned* gp = binned + (size_t)b * CAPB + gbase;
            for (int j = 0; j < c; ++j) gp[j] = buf[b * BUFCAP + j];
        }
    }
}

// ---- K2: csr sort (blocks 0..NB-1) || MFMA gemm (blocks NB..) --------------
__global__ __launch_bounds__(512) void csr_gemm(const unsigned* __restrict__ binned,
                                                const int* __restrict__ binCursor,
                                                int* __restrict__ col,
                                                int2* __restrict__ rowinfo,
                                                float* __restrict__ dinv,
                                                const float* __restrict__ x,
                                                const unsigned short* __restrict__ wbf,
                                                unsigned short* __restrict__ xlin, int N) {
    __shared__ __align__(16) char smem[8 * 16 * WSTRIDE * 2];   // 34.8 KB union
    int t = threadIdx.x;

    if ((int)blockIdx.x < NB) {
        // ---- csr role: counting sort one bin (256 nodes, ~4096 edges)
        int* ldeg = (int*)smem;            // BINSZ
        int* sa   = ldeg + BINSZ;
        int* sb2  = sa + BINSZ;
        int* lcur = sb2 + BINSZ;
        int b = blockIdx.x;
        int s0 = b * CAPB;
        int s1 = s0 + binCursor[b];

        if (t < BINSZ) { ldeg[t] = 0; lcur[t] = 0; }
        __syncthreads();
        for (int i = s0 + t; i < s1; i += 512)
            atomicAdd(&ldeg[binned[i] >> 17], 1);
        __syncthreads();
        if (t < BINSZ) sa[t] = ldeg[t];
        __syncthreads();
        int* src = sa; int* dstp = sb2;
        for (int step = 1; step < BINSZ; step <<= 1) {
            if (t < BINSZ) {
                int v = src[t];
                if (t >= step) v += src[t - step];
                dstp[t] = v;
            }
            __syncthreads();
            int* tmp = src; src = dstp; dstp = tmp;
        }
        if (t < BINSZ) {
            int d = ldeg[t];
            int startoff = src[t] - d;       // exclusive
            int n = (b << BINSHIFT) + t;
            if (n < N) {
                rowinfo[n] = make_int2(s0 + startoff, d);
                dinv[n] = rsqrtf((float)(d + 1));   // +1 self loop
            }
            dstp[t] = startoff;
        }
        __syncthreads();
        for (int i = s0 + t; i < s1; i += 512) {
            unsigned p = binned[i];
            int li = p >> 17;
            col[s0 + dstp[li] + atomicAdd(&lcur[li], 1)] = (int)(p & 0x1FFFFu);
        }
        return;
    }

    // ---- GEMM role: 8 waves x 16 rows = 128 rows per block
    unsigned short* obuf = (unsigned short*)smem;
    int wid = t >> 6, lane = t & 63;
    int m = lane & 15, quad = lane >> 4;
    int row_base = ((int)blockIdx.x - NB) * 128 + wid * 16;

    f32x4 acc[8];
#pragma unroll
    for (int j = 0; j < 8; ++j) acc[j] = (f32x4){0.f, 0.f, 0.f, 0.f};

    int arow = row_base + m;
    if (arow >= N) arow = N - 1;
    const float* xr = x + (size_t)arow * DIM + quad * 8;

#pragma unroll
    for (int kc = 0; kc < 4; ++kc) {
        float4 a0 = *(const float4*)(xr + kc * 32);
        float4 a1 = *(const float4*)(xr + kc * 32 + 4);
        short8 af;
        af[0] = (short)f2bf(a0.x); af[1] = (short)f2bf(a0.y);
        af[2] = (short)f2bf(a0.z); af[3] = (short)f2bf(a0.w);
        af[4] = (short)f2bf(a1.x); af[5] = (short)f2bf(a1.y);
        af[6] = (short)f2bf(a1.z); af[7] = (short)f2bf(a1.w);
#pragma unroll
        for (int jt = 0; jt < 8; ++jt) {
            short8 bf = *(const short8*)&wbf[(jt * 16 + m) * DIM + kc * 32 + quad * 8];
            acc[jt] = __builtin_amdgcn_mfma_f32_16x16x32_bf16(af, bf, acc[jt], 0, 0, 0);
        }
    }

    // epilogue: C layout -> wave-local LDS -> row-major coalesced stores
    unsigned short* ob = &obuf[wid * 16 * WSTRIDE];
#pragma unroll
    for (int jt = 0; jt < 8; ++jt)
#pragma unroll
        for (int r = 0; r < 4; ++r)
            ob[(quad * 4 + r) * WSTRIDE + jt * 16 + m] = f2bf(acc[jt][r]);
    __syncthreads();
#pragma unroll
    for (int it = 0; it < 4; ++it) {
        int idx = it * 64 + lane;
        int r = idx >> 4;
        int cb = idx & 15;
        int grow = row_base + r;
        if (grow < N) {
            short8 v = *(const short8*)&ob[r * WSTRIDE + cb * 8];
            *(short8*)(xlin + (size_t)grow * DIM + cb * 8) = v;
        }
    }
}

// ---- K3: aggregate over gapped CSR: 16 lanes/node, clamped chunks of 4 -----
// (unchanged for clean attribution)

__global__ __launch_bounds__(256) void aggregate(const unsigned short* __restrict__ xlin,
                                                 const int* __restrict__ col,
                                                 const int2* __restrict__ rowinfo,
                                                 const float* __restrict__ dinv,
                                                 const float* __restrict__ bias,
                                                 float* __restrict__ out, int N) {
    int node = blockIdx.x * 16 + (threadIdx.x >> 4);
    int lane = threadIdx.x & 15;          // owns dims 8*lane .. 8*lane+7
    if (node >= N) return;

    float di = dinv[node];
    int2 ri = rowinfo[node];
    int r0 = ri.x, r1 = ri.x + ri.y;

    const uint4* xl = (const uint4*)xlin;     // 8 bf16 per uint4; 16 per row
    float acc[8] = {};
    bf8_axpy(xl[(size_t)node * 16 + lane], di, acc);   // self loop

    for (int i = r0; i < r1; i += 4) {
        int rem = r1 - i;
        int s0 = col[i];
        int s1 = col[rem > 1 ? i + 1 : i];
        int s2 = col[rem > 2 ? i + 2 : i];
        int s3 = col[rem > 3 ? i + 3 : i];
        float d0 = dinv[s0];
        float d1 = rem > 1 ? dinv[s1] : 0.f;
        float d2 = rem > 2 ? dinv[s2] : 0.f;
        float d3 = rem > 3 ? dinv[s3] : 0.f;
        uint4 v0 = xl[(size_t)s0 * 16 + lane];
        uint4 v1 = xl[(size_t)s1 * 16 + lane];
        uint4 v2 = xl[(size_t)s2 * 16 + lane];
        uint4 v3 = xl[(size_t)s3 * 16 + lane];
        bf8_axpy(v0, d0, acc);
        bf8_axpy(v1, d1, acc);
        bf8_axpy(v2, d2, acc);
        bf8_axpy(v3, d3, acc);
    }

    const float4* b4 = (const float4*)(bias + lane * 8);
    float4 bl = b4[0], bh = b4[1];
    float4 olo = make_float4(di * acc[0] + bl.x, di * acc[1] + bl.y,
                             di * acc[2] + bl.z, di * acc[3] + bl.w);
    float4 ohi = make_float4(di * acc[4] + bh.x, di * acc[5] + bh.y,
                             di * acc[6] + bh.z, di * acc[7] + bh.w);
    float4* op = (float4*)(out + (size_t)node * DIM + lane * 8);
    op[0] = olo;
    op[1] = ohi;
}

// ---- launch ----------------------------------------------------------------

extern "C" void kernel_launch(void* const* d_in, const int* in_sizes, int n_in,
                              void* d_out, int out_size, void* d_ws, size_t ws_size,
                              hipStream_t stream) {
    const float* x    = (const float*)d_in[0];
    const int*   ei   = (const int*)d_in[1];
    const float* W    = (const float*)d_in[2];
    const float* bias = (const float*)d_in[3];
    float* out = (float*)d_out;

    const int N = in_sizes[0] / DIM;      // 100000
    const int E = in_sizes[1] / 2;        // 1600000

    char* ws = (char*)d_ws;
    size_t off = 0;
    auto alloc = [&](size_t bytes) { size_t o = off; off = (off + bytes + 255) & ~(size_t)255; return o; };
    unsigned short* xlin = (unsigned short*)(ws + alloc((size_t)N * DIM * 2));   // 25.6 MB
    unsigned* binned = (unsigned*)(ws + alloc((size_t)NB * CAPB * 4));           // 12.8 MB
    int*  col      = (int*)  (ws + alloc((size_t)NB * CAPB * 4));                // 12.8 MB
    int2* rowinfo  = (int2*) (ws + alloc((size_t)N * 8));
    float* dinv    = (float*)(ws + alloc((size_t)N * 4));
    int*  binCursor= (int*)  (ws + alloc((size_t)NB * 4 + 256));
    unsigned short* wbf = (unsigned short*)(ws + alloc((size_t)DIM * DIM * 2));  // 32 KB

    int GB = (N + 127) / 128;             // gemm blocks (782)

    hipMemsetAsync(binCursor, 0, (size_t)NB * 4, stream);
    scatter_ms<<<SBLK + 2, 512, 0, stream>>>(ei, E, binCursor, binned, W, wbf);
    csr_gemm<<<NB + GB, 512, 0, stream>>>(binned, binCursor, col, rowinfo, dinv, x, wbf, xlin, N);
    aggregate<<<(N + 15) / 16, 256, 0, stream>>>(xlin, col, rowinfo, dinv, bias, out, N);
}